// Round 8
// baseline (95.965 us; speedup 1.0000x reference)
//
#include <hip/hip_runtime.h>
#include <hip/hip_bf16.h>

// Problem constants
#define B_N   8192
#define OBS   128
#define HID   512
#define VSZ   256
#define NU    64
#define TOPK  8
#define NOPT  16
#define KEXT  160   // 128 x-cols + 1 bias col + 31 zero pad

typedef __bf16 bf16_t;
typedef __bf16 bf16x8 __attribute__((ext_vector_type(8)));
typedef float  f32x4  __attribute__((ext_vector_type(4)));

// Workspace layout (bytes)
#define OFF_A    0u         // 16 f32
#define OFF_DP   256u       // 256 f32
#define OFF_MT   2048u      // mt[v][k] bf16 256x160 = 81920

// ---------------------------------------------------------------------------
// Kernel 1: fused weff + M^T via MFMA. grid 17 x 256.
//  blocks 0..15: v-tile of 16. Stage weff[:, v0:v0+16] bf16 in LDS (f32 h-sum,
//    one bf16 round), then mt[v][k] = sum_j weff[j][v]*pw[k][j] with
//    mfma_16x16x32_bf16: A-frag from LDS (A[m=v][j]), B-frag streamed from pw
//    rows (B^T[n=k][j], each pw elem used once). 10 k-tiles over 4 waves;
//    tile 8: n==0 is the pb bias row, n>=1 zeros; k 144..159 zero-filled.
//  block 16: A[16] coefficients and Dp.
__launch_bounds__(256)
__global__ void k_wmt(const float* __restrict__ vw, const float* __restrict__ pw,
                      const float* __restrict__ pb, const float* __restrict__ p_w,
                      const float* __restrict__ p_b, const float* __restrict__ vb,
                      bf16_t* __restrict__ mt, float* __restrict__ A,
                      float* __restrict__ Dp) {
    const int tid = threadIdx.x;

    if (blockIdx.x == 16) {
        // A[opt]: 4 waves, wave w handles options 4w..4w+3
        int lane = tid & 63;
        int wvi  = tid >> 6;
        #pragma unroll
        for (int oo = 0; oo < 4; ++oo) {
            int o = wvi * 4 + oo;
            float cur = p_w[o * NU + lane] + p_b[lane];
            float sum = 0.f;
            #pragma unroll
            for (int t = 0; t < TOPK; ++t) {
                float m = cur;
                #pragma unroll
                for (int off = 32; off >= 1; off >>= 1)
                    m = fmaxf(m, __shfl_xor(m, off));
                sum += 1.f / (1.f + expf(-m));
                unsigned long long bal = __ballot(cur == m);
                int first = __ffsll(bal) - 1;   // lowest index: jax tie-break
                if (lane == first) cur = -1e30f;
            }
            if (lane == 0) A[o] = sum * (1.f / NU);
        }
        // Dp[v] = 0.125 * 0.25 * sum_h vb[h*256+v]
        Dp[tid] = 0.03125f * ((vb[tid] + vb[tid + VSZ]) + (vb[tid + 2 * VSZ] + vb[tid + 3 * VSZ]));
        return;
    }

    const int v0 = blockIdx.x * 16;
    __shared__ bf16_t wt[16][520];    // row pad 512->520: debank b128 reads

    // ---- Stage weff^T slice: wt[vi][j] = bf16(0.25 * sum_h vw[j][h*256+v0+vi])
    {
        const int vi = tid & 15;
        const int jb = tid >> 4;      // 0..15
        #pragma unroll 8
        for (int p = 0; p < 32; ++p) {
            int j = p * 16 + jb;
            const float* src = vw + j * (4 * VSZ) + v0 + vi;
            float s = 0.25f * ((src[0] + src[VSZ]) + (src[2 * VSZ] + src[3 * VSZ]));
            wt[vi][j] = (bf16_t)s;
        }
    }
    __syncthreads();

    // ---- MFMA compute: wave w does k-tiles {w, w+4, w+8}
    const int lane = tid & 63;
    const int w    = tid >> 6;
    const int mrow = lane & 15;       // m = v for A-frag; n = k-col for B-frag
    const int quad = lane >> 4;
    const bf16_t* wrow = &wt[mrow][quad * 8];

    for (int t = w; t < 10; t += 4) {
        int  k0   = t * 16;
        bool bias = (t == 8);
        bool act  = bias ? (mrow == 0) : true;
        const float* brow = bias ? (pb + quad * 8)
                                 : (pw + (k0 + mrow) * HID + quad * 8);
        f32x4 acc = {0.f, 0.f, 0.f, 0.f};
        #pragma unroll
        for (int kt = 0; kt < 16; ++kt) {
            bf16x8 a = *(const bf16x8*)(wrow + kt * 32);
            bf16x8 b;
            if (act) {
                f32x4 lo = *(const f32x4*)(brow + kt * 32);
                f32x4 hi = *(const f32x4*)(brow + kt * 32 + 4);
                b[0] = (bf16_t)lo[0]; b[1] = (bf16_t)lo[1];
                b[2] = (bf16_t)lo[2]; b[3] = (bf16_t)lo[3];
                b[4] = (bf16_t)hi[0]; b[5] = (bf16_t)hi[1];
                b[6] = (bf16_t)hi[2]; b[7] = (bf16_t)hi[3];
            } else {
                #pragma unroll
                for (int jj = 0; jj < 8; ++jj) b[jj] = (bf16_t)0.f;
            }
            acc = __builtin_amdgcn_mfma_f32_16x16x32_bf16(a, b, acc, 0, 0, 0);
        }
        // C/D layout: col = lane&15 (k), row = quad*4+r (v)
        #pragma unroll
        for (int r = 0; r < 4; ++r)
            mt[(v0 + quad * 4 + r) * KEXT + k0 + mrow] = (bf16_t)acc[r];
    }

    // ---- zero pad k 144..159 (16 v x 16 k = 256 entries, one per thread)
    {
        int vv = tid >> 4, kk = tid & 15;
        mt[(v0 + vv) * KEXT + 144 + kk] = (bf16_t)0.f;
    }
}

// ---------------------------------------------------------------------------
// Kernel 2: out[b][v] = A[opt[b]] * (x' @ M')[b][v] + Dp[v]
// x' = [x | 1 | 0...], M' = [M ; c ; 0...]; K = 160. f32 x -> bf16 in-register.
// MFMA 16x16x32. Block = 4 waves; wave: 16 rows x 128 cols.
// grid (8192/64, 256/128) = (128, 2).   [unchanged from r6 — proven]
__launch_bounds__(256)
__global__ void k_main(const float* __restrict__ x, const bf16_t* __restrict__ mt,
                       const int* __restrict__ opt, const float* __restrict__ A,
                       const float* __restrict__ Dp, float* __restrict__ out) {
    const int wave = threadIdx.x >> 6;
    const int lane = threadIdx.x & 63;
    const int mrow = lane & 15;
    const int quad = lane >> 4;
    const int r0   = blockIdx.x * 64 + wave * 16;
    const int c0   = blockIdx.y * 128;

    // A-fragments first: all x loads in flight before mt reads
    bf16x8 af[5];
    {
        const float* xr = x + (r0 + mrow) * OBS + quad * 8;
        f32x4 lo[4], hi[4];
        #pragma unroll
        for (int kt = 0; kt < 4; ++kt) {
            lo[kt] = *(const f32x4*)(xr + kt * 32);
            hi[kt] = *(const f32x4*)(xr + kt * 32 + 4);
        }
        #pragma unroll
        for (int kt = 0; kt < 4; ++kt) {
            bf16x8 a;
            a[0] = (bf16_t)lo[kt][0]; a[1] = (bf16_t)lo[kt][1];
            a[2] = (bf16_t)lo[kt][2]; a[3] = (bf16_t)lo[kt][3];
            a[4] = (bf16_t)hi[kt][0]; a[5] = (bf16_t)hi[kt][1];
            a[6] = (bf16_t)hi[kt][2]; a[7] = (bf16_t)hi[kt][3];
            af[kt] = a;
        }
        bf16x8 a;
        #pragma unroll
        for (int j = 0; j < 8; ++j) a[j] = (bf16_t)0.f;
        if (quad == 0) a[0] = (bf16_t)1.0f;   // k=128: bias column
        af[4] = a;
    }

    // per-row scale gathered before the MFMA loop
    float av[4];
    #pragma unroll
    for (int r = 0; r < 4; ++r)
        av[r] = A[opt[r0 + quad * 4 + r]];

    f32x4 acc[8];
    #pragma unroll
    for (int t = 0; t < 8; ++t) acc[t] = (f32x4){0.f, 0.f, 0.f, 0.f};

    const bf16_t* mb = mt + (c0 + mrow) * KEXT + quad * 8;
    #pragma unroll
    for (int kt = 0; kt < 5; ++kt) {
        #pragma unroll
        for (int t = 0; t < 8; ++t) {
            bf16x8 b = *(const bf16x8*)(mb + t * 16 * KEXT + kt * 32);
            acc[t] = __builtin_amdgcn_mfma_f32_16x16x32_bf16(af[kt], b, acc[t], 0, 0, 0);
        }
    }

    // C/D layout: col=lane&15, row=quad*4+reg
    #pragma unroll
    for (int r = 0; r < 4; ++r) {
        int row = r0 + quad * 4 + r;
        float* orow = out + row * VSZ;
        #pragma unroll
        for (int t = 0; t < 8; ++t) {
            int col = c0 + t * 16 + mrow;
            orow[col] = av[r] * acc[t][r] + Dp[col];
        }
    }
}

// ---------------------------------------------------------------------------
extern "C" void kernel_launch(void* const* d_in, const int* in_sizes, int n_in,
                              void* d_out, int out_size, void* d_ws, size_t ws_size,
                              hipStream_t stream) {
    const float* x        = (const float*)d_in[0];
    const int*   option   = (const int*)  d_in[1];
    const float* pre_fc_w = (const float*)d_in[2];
    const float* pre_fc_b = (const float*)d_in[3];
    const float* value_w  = (const float*)d_in[4];
    const float* value_b  = (const float*)d_in[5];
    const float* p_w      = (const float*)d_in[6];
    const float* p_b      = (const float*)d_in[7];
    float* out = (float*)d_out;

    char* ws = (char*)d_ws;
    float*  A    = (float*) (ws + OFF_A);
    float*  Dp   = (float*) (ws + OFF_DP);
    bf16_t* mt   = (bf16_t*)(ws + OFF_MT);

    k_wmt <<<dim3(17), dim3(256), 0, stream>>>(value_w, pre_fc_w, pre_fc_b,
                                               p_w, p_b, value_b, mt, A, Dp);
    k_main<<<dim3(B_N / 64, VSZ / 128), dim3(256), 0, stream>>>(x, mt, option, A, Dp, out);
}

// Round 10
// 89.758 us; speedup vs baseline: 1.0692x; 1.0692x over previous
//
#include <hip/hip_runtime.h>
#include <hip/hip_bf16.h>

// Problem constants
#define B_N   8192
#define OBS   128
#define HID   512
#define VSZ   256
#define NU    64
#define TOPK  8
#define NOPT  16
#define KEXT  160   // 128 x-cols + 1 bias col + 31 zero pad

typedef __bf16 bf16_t;
typedef __bf16 bf16x8 __attribute__((ext_vector_type(8)));
typedef float  f32x4  __attribute__((ext_vector_type(4)));

// Workspace layout (bytes)
#define OFF_A    0u         // 16 f32
#define OFF_DP   256u       // 256 f32
#define OFF_WT   2048u      // weff[j][v] f32 512x256 = 524288
#define OFF_MT   526336u    // mt[v][k] bf16 256x160 = 81920

// ---------------------------------------------------------------------------
// Kernel 1: weff[j][v] = 0.25 * sum_h value_w[j][h*256+v].  grid 512 x 256.
__global__ void k_pre(const float* __restrict__ vw, float* __restrict__ weff) {
    int j = blockIdx.x, v = threadIdx.x;
    const float* r = vw + j * (4 * VSZ);
    weff[j * VSZ + v] = 0.25f * ((r[v] + r[v + VSZ]) + (r[v + 2 * VSZ] + r[v + 3 * VSZ]));
}

// ---------------------------------------------------------------------------
// Kernel 2: grid 130 x 1024.
//  blocks 0..127: mt[v][k] = sum_j pw[k][j] * weff[j][v]   (k = blockIdx)
//  block  128   : c row (k=128) from pre_fc_b
//  block  129   : pad cols 129..159 = 0; A[16] (waves 4..7); Dp (tids 512..767)
__global__ void k_mt(const float* __restrict__ pw, const float* __restrict__ pb,
                     const float* __restrict__ weff, const float* __restrict__ p_w,
                     const float* __restrict__ p_b, const float* __restrict__ vb,
                     bf16_t* __restrict__ mt, float* __restrict__ A,
                     float* __restrict__ Dp) {
    const int tid = threadIdx.x;
    if (blockIdx.x == 129) {
        // pad columns
        if (tid < VSZ) {
            bf16_t* row = mt + tid * KEXT;
            #pragma unroll
            for (int k = 129; k < KEXT; ++k) row[k] = (bf16_t)0.f;
        }
        // A[opt]: waves 4..7, wave w handles options 4(w-4)..4(w-4)+3
        int wvi = tid >> 6;
        if (wvi >= 4 && wvi < 8) {
            int lane = tid & 63;
            #pragma unroll
            for (int oo = 0; oo < 4; ++oo) {
                int o = (wvi - 4) * 4 + oo;
                float cur = p_w[o * NU + lane] + p_b[lane];
                float sum = 0.f;
                #pragma unroll
                for (int t = 0; t < TOPK; ++t) {
                    float m = cur;
                    #pragma unroll
                    for (int off = 32; off >= 1; off >>= 1)
                        m = fmaxf(m, __shfl_xor(m, off));
                    sum += 1.f / (1.f + expf(-m));
                    unsigned long long bal = __ballot(cur == m);
                    int first = __ffsll(bal) - 1;   // lowest index: jax tie-break
                    if (lane == first) cur = -1e30f;
                }
                if (lane == 0) A[o] = sum * (1.f / NU);
            }
        }
        // Dp[v] = 0.125 * 0.25 * sum_h vb[h*256+v]
        if (tid >= 512 && tid < 768) {
            int v = tid & 255;
            Dp[v] = 0.03125f * ((vb[v] + vb[v + VSZ]) + (vb[v + 2 * VSZ] + vb[v + 3 * VSZ]));
        }
        return;
    }

    // compute blocks: one k-column each (r2-proven body)
    int k  = blockIdx.x;
    int v  = tid & 255;
    int jq = tid >> 8;
    __shared__ float red[1024];
    const float* wr = (k < OBS) ? (pw + k * HID) : pb;
    const float* wj = wr + jq * 128;
    const float* wf = weff + (jq * 128) * VSZ + v;
    float a0 = 0.f, a1 = 0.f, a2 = 0.f, a3 = 0.f;
    #pragma unroll 4
    for (int j = 0; j < 128; j += 4) {
        a0 += wj[j + 0] * wf[(j + 0) * VSZ];
        a1 += wj[j + 1] * wf[(j + 1) * VSZ];
        a2 += wj[j + 2] * wf[(j + 2) * VSZ];
        a3 += wj[j + 3] * wf[(j + 3) * VSZ];
    }
    red[tid] = (a0 + a1) + (a2 + a3);
    __syncthreads();
    if (jq == 0)
        mt[v * KEXT + k] = (bf16_t)(((red[v] + red[v + 256]) + (red[v + 512] + red[v + 768])));
}

// ---------------------------------------------------------------------------
// Kernel 3: out[b][v] = A[opt[b]] * (x' @ M')[b][v] + Dp[v]
// x' = [x | 1 | 0...], M' = [M ; c ; 0...]; K = 160. f32 x -> bf16 in-register.
// MFMA 16x16x32. Block = 4 waves; wave: 16 rows x 128 cols.
// grid (8192/64, 256/128) = (128, 2).
__launch_bounds__(256)
__global__ void k_main(const float* __restrict__ x, const bf16_t* __restrict__ mt,
                       const int* __restrict__ opt, const float* __restrict__ A,
                       const float* __restrict__ Dp, float* __restrict__ out) {
    const int wave = threadIdx.x >> 6;
    const int lane = threadIdx.x & 63;
    const int mrow = lane & 15;
    const int quad = lane >> 4;
    const int r0   = blockIdx.x * 64 + wave * 16;
    const int c0   = blockIdx.y * 128;

    // A-fragments first: all x loads in flight before mt reads
    bf16x8 af[5];
    {
        const float* xr = x + (r0 + mrow) * OBS + quad * 8;
        f32x4 lo[4], hi[4];
        #pragma unroll
        for (int kt = 0; kt < 4; ++kt) {
            lo[kt] = *(const f32x4*)(xr + kt * 32);
            hi[kt] = *(const f32x4*)(xr + kt * 32 + 4);
        }
        #pragma unroll
        for (int kt = 0; kt < 4; ++kt) {
            bf16x8 a;
            a[0] = (bf16_t)lo[kt][0]; a[1] = (bf16_t)lo[kt][1];
            a[2] = (bf16_t)lo[kt][2]; a[3] = (bf16_t)lo[kt][3];
            a[4] = (bf16_t)hi[kt][0]; a[5] = (bf16_t)hi[kt][1];
            a[6] = (bf16_t)hi[kt][2]; a[7] = (bf16_t)hi[kt][3];
            af[kt] = a;
        }
        bf16x8 a;
        #pragma unroll
        for (int j = 0; j < 8; ++j) a[j] = (bf16_t)0.f;
        if (quad == 0) a[0] = (bf16_t)1.0f;   // k=128: bias column
        af[4] = a;
    }

    // per-row scale gathered before the MFMA loop
    float av[4];
    #pragma unroll
    for (int r = 0; r < 4; ++r)
        av[r] = A[opt[r0 + quad * 4 + r]];

    f32x4 acc[8];
    #pragma unroll
    for (int t = 0; t < 8; ++t) acc[t] = (f32x4){0.f, 0.f, 0.f, 0.f};

    const bf16_t* mb = mt + (c0 + mrow) * KEXT + quad * 8;
    #pragma unroll
    for (int kt = 0; kt < 5; ++kt) {
        #pragma unroll
        for (int t = 0; t < 8; ++t) {
            bf16x8 b = *(const bf16x8*)(mb + t * 16 * KEXT + kt * 32);
            acc[t] = __builtin_amdgcn_mfma_f32_16x16x32_bf16(af[kt], b, acc[t], 0, 0, 0);
        }
    }

    // C/D layout: col=lane&15, row=quad*4+reg
    #pragma unroll
    for (int r = 0; r < 4; ++r) {
        int row = r0 + quad * 4 + r;
        float* orow = out + row * VSZ;
        #pragma unroll
        for (int t = 0; t < 8; ++t) {
            int col = c0 + t * 16 + mrow;
            orow[col] = av[r] * acc[t][r] + Dp[col];
        }
    }
}

// ---------------------------------------------------------------------------
extern "C" void kernel_launch(void* const* d_in, const int* in_sizes, int n_in,
                              void* d_out, int out_size, void* d_ws, size_t ws_size,
                              hipStream_t stream) {
    const float* x        = (const float*)d_in[0];
    const int*   option   = (const int*)  d_in[1];
    const float* pre_fc_w = (const float*)d_in[2];
    const float* pre_fc_b = (const float*)d_in[3];
    const float* value_w  = (const float*)d_in[4];
    const float* value_b  = (const float*)d_in[5];
    const float* p_w      = (const float*)d_in[6];
    const float* p_b      = (const float*)d_in[7];
    float* out = (float*)d_out;

    char* ws = (char*)d_ws;
    float*  A    = (float*) (ws + OFF_A);
    float*  Dp   = (float*) (ws + OFF_DP);
    float*  weff = (float*) (ws + OFF_WT);
    bf16_t* mt   = (bf16_t*)(ws + OFF_MT);

    k_pre <<<dim3(HID), dim3(VSZ), 0, stream>>>(value_w, weff);
    k_mt  <<<dim3(130), dim3(1024), 0, stream>>>(pre_fc_w, pre_fc_b, weff,
                                                 p_w, p_b, value_b, mt, A, Dp);
    k_main<<<dim3(B_N / 64, VSZ / 128), dim3(256), 0, stream>>>(x, mt, option, A, Dp, out);
}